// Round 11
// baseline (582.864 us; speedup 1.0000x reference)
//
#include <hip/hip_runtime.h>
#include <stdint.h>

#define Bn 16384
#define Dn 64
#define Hn 256

typedef short bf16x8 __attribute__((ext_vector_type(8)));
typedef float f32x4 __attribute__((ext_vector_type(4)));

__device__ __forceinline__ unsigned f2bf1(float f) {
  unsigned u = __float_as_uint(f);
  return (u + 0x7FFFu + ((u >> 16) & 1u)) >> 16;   // RNE to bf16
}

// ---------- pack W2 (fp32 [D][H][H]) into MFMA B-fragment-linear bf16 ----------
// layout: [d][kk(8)][nj(16)][lane(64)][8 bf16]; lane holds B[k=kk*32+(lane>>4)*8+b][n=nj*16+(lane&15)]
__global__ __launch_bounds__(256) void pack_w2(const float* __restrict__ W2,
                                               unsigned short* __restrict__ Bp) {
  int g = blockIdx.x * 4 + (threadIdx.x >> 6);   // 8192 units
  int lane = threadIdx.x & 63;
  int d  = g >> 7;
  int kk = (g >> 4) & 7;
  int nj = g & 15;
  int k0 = kk * 32 + ((lane >> 4) << 3);
  int n  = nj * 16 + (lane & 15);
  const float* src = W2 + ((size_t)d * Hn + k0) * Hn + n;
  unsigned t[8];
  #pragma unroll
  for (int b = 0; b < 8; ++b) t[b] = f2bf1(src[(size_t)b * Hn]);
  uint4 w;
  w.x = t[0] | (t[1] << 16);
  w.y = t[2] | (t[3] << 16);
  w.z = t[4] | (t[5] << 16);
  w.w = t[6] | (t[7] << 16);
  size_t off = (((size_t)g) * 64 + lane) * 8;    // elements
  *(uint4*)(Bp + off) = w;
}

// ---------- transpose small tail weights for coalesced reads ----------
__global__ __launch_bounds__(256) void prep_t(
    const float* __restrict__ Wq, const float* __restrict__ Wk,
    const float* __restrict__ Wc1, const float* __restrict__ Ws,
    float* __restrict__ WqT, float* __restrict__ WkT,
    float* __restrict__ Wc1T, float* __restrict__ WsT) {
  int t = blockIdx.x * 256 + threadIdx.x;   // 16384
  int h = t >> 6, dd = t & 63;
  WqT[dd * 256 + h]  = Wq[h * 64 + dd];
  WkT[dd * 256 + h]  = Wk[h * 64 + dd];
  Wc1T[dd * 256 + h] = Wc1[h * 64 + dd];
  WsT[h * 64 + dd]   = Ws[dd * 256 + h];
}

// ---------- main fused kernel: multi-tile block, interleaved a1, swapped MFMA ----
// 1024 blocks = 64 d x 16 chunks (4/CU, all co-resident). 256 threads = 4
// waves 1M x 4N; wave = 32 rows x 64 cols; BM=32; T=32 tiles per block.
// a1 (32 rows x 256 k = 16 frag-slots) streamed via 2x16KB LDS dbuf: wave w
// computes stages {2w,2w+1} of tile t+1 inside tile t's K-loop. B fragments
// JIT-loaded from packed Bp (L1/L2-hot across tiles). Swapped-operand MFMA
// (row at lane&15, col at g*4+i) makes the epilogue 2 shfls/mi; b2 folds
// into acc init. One __syncthreads per tile.
__global__ __launch_bounds__(256, 4) void gemm_hcat(
    const float* __restrict__ x, const float* __restrict__ W1,
    const float* __restrict__ b1, const float* __restrict__ b2,
    const float* __restrict__ W3, const float* __restrict__ b3,
    const unsigned short* __restrict__ Bp, float* __restrict__ hcT) {
  __shared__ char As[2][16384];   // [slot(16)=st*2+gm][lane(64)][16B]
  __shared__ float P[2][4][32];

  int bid = blockIdx.x;
  int xcd = bid & 7;
  int dl = (bid >> 3) & 7;
  int chunk = bid >> 6;            // 0..15
  int d = xcd * 8 + dl;            // 8 d per XCD -> Bp slice L2-resident
  int base = chunk * 1024;         // 32 tiles of 32 rows

  int tid = threadIdx.x;
  int lane = tid & 63;
  int w = tid >> 6;                // wave id = wn; also owns a1 stages {2w,2w+1}
  int l15 = lane & 15;
  int g = lane >> 4;

  const unsigned short* BpD = Bp + (size_t)d * 65536;
  const float* W1d = W1 + d * Hn;
  const float* b1d = b1 + d * Hn;
  const float* b2d = b2 + d * Hn;
  const float* W3d = W3 + d * Hn;
  float b3d = b3[d];

  // a1 slot (st, gm): row = gm*16+l15, k = st*32+g*8+(0..7) of the NEXT tile
  #define A1SLOT(wbuf, st, gm, xv)                                              \
    {                                                                           \
      int k0 = (st) * 32 + (g << 3);                                            \
      float4 wa = *(const float4*)(W1d + k0);                                   \
      float4 wb = *(const float4*)(W1d + k0 + 4);                               \
      float4 ba = *(const float4*)(b1d + k0);                                   \
      float4 bb = *(const float4*)(b1d + k0 + 4);                               \
      float v0 = fmaxf(fmaf((xv), wa.x, ba.x), 0.f);                            \
      float v1 = fmaxf(fmaf((xv), wa.y, ba.y), 0.f);                            \
      float v2 = fmaxf(fmaf((xv), wa.z, ba.z), 0.f);                            \
      float v3 = fmaxf(fmaf((xv), wa.w, ba.w), 0.f);                            \
      float v4 = fmaxf(fmaf((xv), wb.x, bb.x), 0.f);                            \
      float v5 = fmaxf(fmaf((xv), wb.y, bb.y), 0.f);                            \
      float v6 = fmaxf(fmaf((xv), wb.z, bb.z), 0.f);                            \
      float v7 = fmaxf(fmaf((xv), wb.w, bb.w), 0.f);                            \
      uint4 pk;                                                                 \
      asm("v_cvt_pk_bf16_f32 %0, %1, %2" : "=v"(pk.x) : "v"(v0), "v"(v1));      \
      asm("v_cvt_pk_bf16_f32 %0, %1, %2" : "=v"(pk.y) : "v"(v2), "v"(v3));      \
      asm("v_cvt_pk_bf16_f32 %0, %1, %2" : "=v"(pk.z) : "v"(v4), "v"(v5));      \
      asm("v_cvt_pk_bf16_f32 %0, %1, %2" : "=v"(pk.w) : "v"(v6), "v"(v7));      \
      *(uint4*)((wbuf) + ((((st) << 1) + (gm)) << 10) + (lane << 4)) = pk;      \
    }

  // prologue: a1 for tile 0 (each wave fills its two stages, both row-groups)
  {
    float x0 = x[(size_t)(base + l15) * Dn + d];
    float x1 = x[(size_t)(base + 16 + l15) * Dn + d];
    A1SLOT(As[0], 2 * w, 0, x0);
    A1SLOT(As[0], 2 * w, 1, x1);
    A1SLOT(As[0], 2 * w + 1, 0, x0);
    A1SLOT(As[0], 2 * w + 1, 1, x1);
  }
  __syncthreads();

  for (int t = 0; t < 32; ++t) {
    int p = t & 1;
    const char* rb = As[p];
    char* wbuf = As[p ^ 1];
    bool pre = (t < 31);
    float xn0 = 0.f, xn1 = 0.f;
    if (pre) {
      xn0 = x[(size_t)(base + (t + 1) * 32 + l15) * Dn + d];
      xn1 = x[(size_t)(base + (t + 1) * 32 + 16 + l15) * Dn + d];
    }

    // acc init = b2 (folded); col = (wn*4+nj)*16 + g*4 + i
    f32x4 acc[2][4];
    #pragma unroll
    for (int nj = 0; nj < 4; ++nj) {
      float4 bv = *(const float4*)(b2d + (((w << 2) + nj) << 4) + (g << 2));
      f32x4 iv = {bv.x, bv.y, bv.z, bv.w};
      acc[0][nj] = iv;
      acc[1][nj] = iv;
    }

    #pragma unroll
    for (int s = 0; s < 8; ++s) {
      bf16x8 bfr[4];
      #pragma unroll
      for (int nj = 0; nj < 4; ++nj)
        bfr[nj] = *(const bf16x8*)(BpD + (((s * 16 + (w << 2) + nj) << 6) + lane) * 8);
      bf16x8 af0 = *(const bf16x8*)(rb + ((s << 1) << 10) + (lane << 4));
      bf16x8 af1 = *(const bf16x8*)(rb + (((s << 1) + 1) << 10) + (lane << 4));

      if (pre && s == 0) { A1SLOT(wbuf, 2 * w, 0, xn0); }
      if (pre && s == 2) { A1SLOT(wbuf, 2 * w, 1, xn1); }
      if (pre && s == 4) { A1SLOT(wbuf, 2 * w + 1, 0, xn0); }
      if (pre && s == 6) { A1SLOT(wbuf, 2 * w + 1, 1, xn1); }

      __builtin_amdgcn_s_setprio(1);
      #pragma unroll
      for (int nj = 0; nj < 4; ++nj) {
        acc[0][nj] = __builtin_amdgcn_mfma_f32_16x16x32_bf16(bfr[nj], af0, acc[0][nj], 0, 0, 0);
        acc[1][nj] = __builtin_amdgcn_mfma_f32_16x16x32_bf16(bfr[nj], af1, acc[1][nj], 0, 0, 0);
      }
      __builtin_amdgcn_s_setprio(0);
    }

    // epilogue: relu . W3 over this wave's 64 cols; rows at l15, 2 shfls
    #pragma unroll
    for (int mi = 0; mi < 2; ++mi) {
      float ph = 0.f;
      #pragma unroll
      for (int nj = 0; nj < 4; ++nj) {
        float4 wv = *(const float4*)(W3d + (((w << 2) + nj) << 4) + (g << 2));
        ph = fmaf(fmaxf(acc[mi][nj][0], 0.f), wv.x, ph);
        ph = fmaf(fmaxf(acc[mi][nj][1], 0.f), wv.y, ph);
        ph = fmaf(fmaxf(acc[mi][nj][2], 0.f), wv.z, ph);
        ph = fmaf(fmaxf(acc[mi][nj][3], 0.f), wv.w, ph);
      }
      ph += __shfl_xor(ph, 16);
      ph += __shfl_xor(ph, 32);
      if (lane < 16) P[p][w][(mi << 4) + l15] = ph;
    }
    __syncthreads();   // a1(t+1) written + P(t) visible
    if (tid < 32) {
      float h = P[p][0][tid] + P[p][1][tid] + P[p][2][tid] + P[p][3][tid] + b3d;
      hcT[(size_t)d * Bn + base + t * 32 + tid] = h;
    }
  }
  #undef A1SLOT
}

// ---------- tail: attention fusion + cross MLP + g_func; 4 rows per wave ----------
__global__ __launch_bounds__(256) void fused_tail(
    const float* __restrict__ hcT, const float* __restrict__ WqT,
    const float* __restrict__ bq, const float* __restrict__ WkT,
    const float* __restrict__ bk, const float* __restrict__ WsT,
    const float* __restrict__ bs, const float* __restrict__ Wc1T,
    const float* __restrict__ bc1, const float* __restrict__ Wc2,
    const float* __restrict__ bc2, const float* __restrict__ Wg1,
    const float* __restrict__ bg1, const float* __restrict__ Wg2,
    const float* __restrict__ bg2, float* __restrict__ out) {
  __shared__ float hcs[4][4][64];
  __shared__ float ts[4][4][256];
  int wid = threadIdx.x >> 6;
  int lane = threadIdx.x & 63;
  int r0 = (blockIdx.x * 4 + wid) * 4;                 // 4 rows per wave
  float4 hc4 = *(const float4*)(hcT + (size_t)lane * Bn + r0);   // lane <-> feature d
  hcs[wid][0][lane] = hc4.x;
  hcs[wid][1][lane] = hc4.y;
  hcs[wid][2][lane] = hc4.z;
  hcs[wid][3][lane] = hc4.w;
  __syncthreads();

  float qv[4][4], kv[4][4], cv[4][4];
  #pragma unroll
  for (int j = 0; j < 4; ++j) {
    int h = lane + 64 * j;
    float bqv = bq[h], bkv = bk[h], bcv = bc1[h];
    #pragma unroll
    for (int r = 0; r < 4; ++r) { qv[r][j] = bqv; kv[r][j] = bkv; cv[r][j] = bcv; }
  }
  for (int d2 = 0; d2 < 64; ++d2) {
    float hv0 = hcs[wid][0][d2], hv1 = hcs[wid][1][d2];
    float hv2 = hcs[wid][2][d2], hv3 = hcs[wid][3][d2];
    #pragma unroll
    for (int j = 0; j < 4; ++j) {
      int h = lane + 64 * j;
      float wq = WqT[d2 * 256 + h], wk = WkT[d2 * 256 + h], wc = Wc1T[d2 * 256 + h];
      qv[0][j] = fmaf(wq, hv0, qv[0][j]); qv[1][j] = fmaf(wq, hv1, qv[1][j]);
      qv[2][j] = fmaf(wq, hv2, qv[2][j]); qv[3][j] = fmaf(wq, hv3, qv[3][j]);
      kv[0][j] = fmaf(wk, hv0, kv[0][j]); kv[1][j] = fmaf(wk, hv1, kv[1][j]);
      kv[2][j] = fmaf(wk, hv2, kv[2][j]); kv[3][j] = fmaf(wk, hv3, kv[3][j]);
      cv[0][j] = fmaf(wc, hv0, cv[0][j]); cv[1][j] = fmaf(wc, hv1, cv[1][j]);
      cv[2][j] = fmaf(wc, hv2, cv[2][j]); cv[3][j] = fmaf(wc, hv3, cv[3][j]);
    }
  }
  #pragma unroll
  for (int r = 0; r < 4; ++r)
    #pragma unroll
    for (int j = 0; j < 4; ++j)
      ts[wid][r][lane + 64 * j] = tanhf(qv[r][j] * kv[r][j]);
  __syncthreads();

  float sc[4];
  { float b = bs[lane]; sc[0] = b; sc[1] = b; sc[2] = b; sc[3] = b; }
  for (int h2 = 0; h2 < 256; ++h2) {
    float w = WsT[h2 * 64 + lane];
    sc[0] = fmaf(w, ts[wid][0][h2], sc[0]);
    sc[1] = fmaf(w, ts[wid][1][h2], sc[1]);
    sc[2] = fmaf(w, ts[wid][2][h2], sc[2]);
    sc[3] = fmaf(w, ts[wid][3][h2], sc[3]);
  }

  float hcr[4] = {hc4.x, hc4.y, hc4.z, hc4.w};
  float res[4];
  #pragma unroll
  for (int r = 0; r < 4; ++r) {
    float s = sc[r];
    float mx = s;
    #pragma unroll
    for (int off = 1; off < 64; off <<= 1) mx = fmaxf(mx, __shfl_xor(mx, off));
    float e = __expf(s - mx);
    float se = e;
    #pragma unroll
    for (int off = 1; off < 64; off <<= 1) se += __shfl_xor(se, off);
    float wgt = hcr[r] * (e / se);
    #pragma unroll
    for (int off = 1; off < 64; off <<= 1) wgt += __shfl_xor(wgt, off);
    float cp = 0.f;
    #pragma unroll
    for (int j = 0; j < 4; ++j) cp = fmaf(fmaxf(cv[r][j], 0.f), Wc2[lane + 64 * j], cp);
    #pragma unroll
    for (int off = 1; off < 64; off <<= 1) cp += __shfl_xor(cp, off);
    float comb = wgt + cp + bc2[0];
    float fp = 0.f;
    #pragma unroll
    for (int j = 0; j < 4; ++j) {
      int h = lane + 64 * j;
      fp = fmaf(fmaxf(fmaf(comb, Wg1[h], bg1[h]), 0.f), Wg2[h], fp);
    }
    #pragma unroll
    for (int off = 1; off < 64; off <<= 1) fp += __shfl_xor(fp, off);
    res[r] = fp + bg2[0];
  }
  if (lane == 0) {
    float4 o = make_float4(res[0], res[1], res[2], res[3]);
    *(float4*)(out + r0) = o;
  }
}

extern "C" void kernel_launch(void* const* d_in, const int* in_sizes, int n_in,
                              void* d_out, int out_size, void* d_ws, size_t ws_size,
                              hipStream_t stream) {
  const float* x   = (const float*)d_in[0];
  const float* W1  = (const float*)d_in[1];
  const float* b1  = (const float*)d_in[2];
  const float* W2  = (const float*)d_in[3];
  const float* b2  = (const float*)d_in[4];
  const float* W3  = (const float*)d_in[5];
  const float* b3  = (const float*)d_in[6];
  const float* Wq  = (const float*)d_in[7];
  const float* bq  = (const float*)d_in[8];
  const float* Wk  = (const float*)d_in[9];
  const float* bk  = (const float*)d_in[10];
  const float* Ws  = (const float*)d_in[11];
  const float* bs  = (const float*)d_in[12];
  const float* Wc1 = (const float*)d_in[13];
  const float* bc1 = (const float*)d_in[14];
  const float* Wc2 = (const float*)d_in[15];
  const float* bc2 = (const float*)d_in[16];
  const float* Wg1 = (const float*)d_in[17];
  const float* bg1 = (const float*)d_in[18];
  const float* Wg2 = (const float*)d_in[19];
  const float* bg2 = (const float*)d_in[20];

  unsigned short* Bp = (unsigned short*)d_ws;               // 8,388,608 B
  float* hcT  = (float*)((char*)d_ws + 8388608);            // 4,194,304 B
  float* WqT  = (float*)((char*)d_ws + 12582912);
  float* WkT  = WqT + 16384;
  float* Wc1T = WkT + 16384;
  float* WsT  = Wc1T + 16384;

  pack_w2<<<2048, 256, 0, stream>>>(W2, Bp);
  prep_t<<<64, 256, 0, stream>>>(Wq, Wk, Wc1, Ws, WqT, WkT, Wc1T, WsT);
  gemm_hcat<<<1024, 256, 0, stream>>>(x, W1, b1, b2, W3, b3, Bp, hcT);
  fused_tail<<<1024, 256, 0, stream>>>(hcT, WqT, bq, WkT, bk, WsT, bs, Wc1T, bc1,
                                       Wc2, bc2, Wg1, bg1, Wg2, bg2, (float*)d_out);
}

// Round 12
// 271.096 us; speedup vs baseline: 2.1500x; 2.1500x over previous
//
#include <hip/hip_runtime.h>
#include <stdint.h>

#define Bn 16384
#define Dn 64
#define Hn 256

typedef short bf16x8 __attribute__((ext_vector_type(8)));
typedef float f32x4 __attribute__((ext_vector_type(4)));

__device__ __forceinline__ unsigned f2bf1(float f) {
  unsigned u = __float_as_uint(f);
  return (u + 0x7FFFu + ((u >> 16) & 1u)) >> 16;   // RNE to bf16
}

// ---------- pack W2 (fp32 [D][H][H]) into MFMA B-fragment-linear bf16 ----------
// layout: [d][kk(8)][nj(16)][lane(64)][8 bf16]; lane holds B[k=kk*32+(lane>>4)*8+b][n=nj*16+(lane&15)]
__global__ __launch_bounds__(256) void pack_w2(const float* __restrict__ W2,
                                               unsigned short* __restrict__ Bp) {
  int g = blockIdx.x * 4 + (threadIdx.x >> 6);   // 8192 units
  int lane = threadIdx.x & 63;
  int d  = g >> 7;
  int kk = (g >> 4) & 7;
  int nj = g & 15;
  int k0 = kk * 32 + ((lane >> 4) << 3);
  int n  = nj * 16 + (lane & 15);
  const float* src = W2 + ((size_t)d * Hn + k0) * Hn + n;
  unsigned t[8];
  #pragma unroll
  for (int b = 0; b < 8; ++b) t[b] = f2bf1(src[(size_t)b * Hn]);
  uint4 w;
  w.x = t[0] | (t[1] << 16);
  w.y = t[2] | (t[3] << 16);
  w.z = t[4] | (t[5] << 16);
  w.w = t[6] | (t[7] << 16);
  size_t off = (((size_t)g) * 64 + lane) * 8;    // elements
  *(uint4*)(Bp + off) = w;
}

// ---------- transpose small tail weights for coalesced reads ----------
__global__ __launch_bounds__(256) void prep_t(
    const float* __restrict__ Wq, const float* __restrict__ Wk,
    const float* __restrict__ Wc1, const float* __restrict__ Ws,
    float* __restrict__ WqT, float* __restrict__ WkT,
    float* __restrict__ Wc1T, float* __restrict__ WsT) {
  int t = blockIdx.x * 256 + threadIdx.x;   // 16384
  int h = t >> 6, dd = t & 63;
  WqT[dd * 256 + h]  = Wq[h * 64 + dd];
  WkT[dd * 256 + h]  = Wk[h * 64 + dd];
  Wc1T[dd * 256 + h] = Wc1[h * 64 + dd];
  WsT[h * 64 + dd]   = Ws[dd * 256 + h];
}

// ---------- persistent fused GEMM: 1M x 8N, all-persistent registers ----------
// 512 blocks = 8 xcd x 8 dlocal x 8 chunks (2/CU, ALL co-resident).
// 512 threads = 8 waves 1M x 8N: wave = 32 rows x 32 cols; T=64 tiles of 32
// rows per block. Persistent per wave: breg[16] (its 32 cols x K=256, 64
// VGPR, gathered once from packed Bp) + W1/b1 k-slice (16 VGPR). a1 via
// 2x16KB LDS dbuf: wave w computes stage w of tile t+1 inside tile t's
// K-loop (R6's proven spill-free pattern). Swapped-operand MFMA -> rows at
// l15, 2-shfl epilogue; b2 in acc init. ~120 regs -> 4 waves/SIMD.
__global__ __launch_bounds__(512, 4) void gemm_hcat(
    const float* __restrict__ x, const float* __restrict__ W1,
    const float* __restrict__ b1, const float* __restrict__ b2,
    const float* __restrict__ W3, const float* __restrict__ b3,
    const unsigned short* __restrict__ Bp, float* __restrict__ hcT) {
  __shared__ char As[2][16384];   // [slot(16)=s*2+gm][lane(64)][16B]
  __shared__ float P[2][8][32];

  int bid = blockIdx.x;
  int xcd = bid & 7;
  int dl = (bid >> 3) & 7;
  int chunk = bid >> 6;            // 0..7
  int d = xcd * 8 + dl;            // 8 d per XCD -> Bp slice + x lines L2-hot
  int base = chunk * 2048;         // 64 tiles of 32 rows

  int tid = threadIdx.x;
  int lane = tid & 63;
  int w = tid >> 6;                // wave id = wn; owns cols w*32.., a1 stage w
  int l15 = lane & 15;
  int g = lane >> 4;

  const unsigned short* BpD = Bp + (size_t)d * 65536;
  const float* b2d = b2 + d * Hn;
  const float* W3d = W3 + d * Hn;
  float b3d = b3[d];

  // persistent W1/b1 k-slice: this thread always handles k = w*32 + g*8 + (0..7)
  int k0 = w * 32 + (g << 3);
  float4 w1a = *(const float4*)(W1 + d * Hn + k0);
  float4 w1b = *(const float4*)(W1 + d * Hn + k0 + 4);
  float4 b1a = *(const float4*)(b1 + d * Hn + k0);
  float4 b1b = *(const float4*)(b1 + d * Hn + k0 + 4);

  // persistent breg[16]: this wave's 32 cols (nj = 2w, 2w+1) x full K
  bf16x8 breg[16];
  #pragma unroll
  for (int s = 0; s < 8; ++s)
    #pragma unroll
    for (int j = 0; j < 2; ++j)
      breg[s * 2 + j] = *(const bf16x8*)(BpD + (((s * 16 + 2 * w + j) << 6) + lane) * 8);

  // a1 slot (stage=w, row-group gm): row = gm*16+l15, k = w*32+g*8+(0..7)
  #define A1SLOT(wbuf, gm, xv)                                                  \
    {                                                                           \
      float v0 = fmaxf(fmaf((xv), w1a.x, b1a.x), 0.f);                          \
      float v1 = fmaxf(fmaf((xv), w1a.y, b1a.y), 0.f);                          \
      float v2 = fmaxf(fmaf((xv), w1a.z, b1a.z), 0.f);                          \
      float v3 = fmaxf(fmaf((xv), w1a.w, b1a.w), 0.f);                          \
      float v4 = fmaxf(fmaf((xv), w1b.x, b1b.x), 0.f);                          \
      float v5 = fmaxf(fmaf((xv), w1b.y, b1b.y), 0.f);                          \
      float v6 = fmaxf(fmaf((xv), w1b.z, b1b.z), 0.f);                          \
      float v7 = fmaxf(fmaf((xv), w1b.w, b1b.w), 0.f);                          \
      uint4 pk;                                                                 \
      asm("v_cvt_pk_bf16_f32 %0, %1, %2" : "=v"(pk.x) : "v"(v0), "v"(v1));      \
      asm("v_cvt_pk_bf16_f32 %0, %1, %2" : "=v"(pk.y) : "v"(v2), "v"(v3));      \
      asm("v_cvt_pk_bf16_f32 %0, %1, %2" : "=v"(pk.z) : "v"(v4), "v"(v5));      \
      asm("v_cvt_pk_bf16_f32 %0, %1, %2" : "=v"(pk.w) : "v"(v6), "v"(v7));      \
      *(uint4*)((wbuf) + (((w << 1) + (gm)) << 10) + (lane << 4)) = pk;         \
    }

  // prologue: a1 for tile 0
  {
    float x0 = x[(size_t)(base + l15) * Dn + d];
    float x1 = x[(size_t)(base + 16 + l15) * Dn + d];
    A1SLOT(As[0], 0, x0);
    A1SLOT(As[0], 1, x1);
  }
  __syncthreads();

  for (int t = 0; t < 64; ++t) {
    int p = t & 1;
    const char* rb = As[p];
    char* wbuf = As[p ^ 1];
    bool pre = (t < 63);
    float xn0 = 0.f, xn1 = 0.f;
    if (pre) {
      xn0 = x[(size_t)(base + (t + 1) * 32 + l15) * Dn + d];
      xn1 = x[(size_t)(base + (t + 1) * 32 + 16 + l15) * Dn + d];
    }

    // acc init = b2 (folded); col = w*32 + nj*16 + g*4 + i
    f32x4 acc[2][2];
    {
      float4 bv0 = *(const float4*)(b2d + (w << 5) + (g << 2));
      float4 bv1 = *(const float4*)(b2d + (w << 5) + 16 + (g << 2));
      f32x4 i0 = {bv0.x, bv0.y, bv0.z, bv0.w};
      f32x4 i1 = {bv1.x, bv1.y, bv1.z, bv1.w};
      acc[0][0] = i0; acc[1][0] = i0;
      acc[0][1] = i1; acc[1][1] = i1;
    }

    #pragma unroll
    for (int s = 0; s < 8; ++s) {
      bf16x8 af0 = *(const bf16x8*)(rb + ((s << 1) << 10) + (lane << 4));
      bf16x8 af1 = *(const bf16x8*)(rb + (((s << 1) + 1) << 10) + (lane << 4));
      if (pre && s == 2) { A1SLOT(wbuf, 0, xn0); }
      if (pre && s == 5) { A1SLOT(wbuf, 1, xn1); }
      __builtin_amdgcn_s_setprio(1);
      acc[0][0] = __builtin_amdgcn_mfma_f32_16x16x32_bf16(breg[s * 2 + 0], af0, acc[0][0], 0, 0, 0);
      acc[1][0] = __builtin_amdgcn_mfma_f32_16x16x32_bf16(breg[s * 2 + 0], af1, acc[1][0], 0, 0, 0);
      acc[0][1] = __builtin_amdgcn_mfma_f32_16x16x32_bf16(breg[s * 2 + 1], af0, acc[0][1], 0, 0, 0);
      acc[1][1] = __builtin_amdgcn_mfma_f32_16x16x32_bf16(breg[s * 2 + 1], af1, acc[1][1], 0, 0, 0);
      __builtin_amdgcn_s_setprio(0);
    }

    // epilogue: relu . W3 over this wave's 32 cols; rows at l15, 2 shfls
    {
      float4 wv0 = *(const float4*)(W3d + (w << 5) + (g << 2));
      float4 wv1 = *(const float4*)(W3d + (w << 5) + 16 + (g << 2));
      #pragma unroll
      for (int mi = 0; mi < 2; ++mi) {
        float ph;
        ph = fmaxf(acc[mi][0][0], 0.f) * wv0.x;
        ph = fmaf(fmaxf(acc[mi][0][1], 0.f), wv0.y, ph);
        ph = fmaf(fmaxf(acc[mi][0][2], 0.f), wv0.z, ph);
        ph = fmaf(fmaxf(acc[mi][0][3], 0.f), wv0.w, ph);
        ph = fmaf(fmaxf(acc[mi][1][0], 0.f), wv1.x, ph);
        ph = fmaf(fmaxf(acc[mi][1][1], 0.f), wv1.y, ph);
        ph = fmaf(fmaxf(acc[mi][1][2], 0.f), wv1.z, ph);
        ph = fmaf(fmaxf(acc[mi][1][3], 0.f), wv1.w, ph);
        ph += __shfl_xor(ph, 16);
        ph += __shfl_xor(ph, 32);
        if (lane < 16) P[p][w][(mi << 4) + l15] = ph;
      }
    }
    __syncthreads();   // a1(t+1) written + P(t) visible
    if (tid < 32) {
      const float* pp = &P[p][0][tid];
      float h = ((pp[0] + pp[32]) + (pp[64] + pp[96])) +
                ((pp[128] + pp[160]) + (pp[192] + pp[224])) + b3d;
      hcT[(size_t)d * Bn + base + t * 32 + tid] = h;
    }
  }
  #undef A1SLOT
}

// ---------- tail: attention fusion + cross MLP + g_func; 4 rows per wave ----------
__global__ __launch_bounds__(256) void fused_tail(
    const float* __restrict__ hcT, const float* __restrict__ WqT,
    const float* __restrict__ bq, const float* __restrict__ WkT,
    const float* __restrict__ bk, const float* __restrict__ WsT,
    const float* __restrict__ bs, const float* __restrict__ Wc1T,
    const float* __restrict__ bc1, const float* __restrict__ Wc2,
    const float* __restrict__ bc2, const float* __restrict__ Wg1,
    const float* __restrict__ bg1, const float* __restrict__ Wg2,
    const float* __restrict__ bg2, float* __restrict__ out) {
  __shared__ float hcs[4][4][64];
  __shared__ float ts[4][4][256];
  int wid = threadIdx.x >> 6;
  int lane = threadIdx.x & 63;
  int r0 = (blockIdx.x * 4 + wid) * 4;                 // 4 rows per wave
  float4 hc4 = *(const float4*)(hcT + (size_t)lane * Bn + r0);   // lane <-> feature d
  hcs[wid][0][lane] = hc4.x;
  hcs[wid][1][lane] = hc4.y;
  hcs[wid][2][lane] = hc4.z;
  hcs[wid][3][lane] = hc4.w;
  __syncthreads();

  float qv[4][4], kv[4][4], cv[4][4];
  #pragma unroll
  for (int j = 0; j < 4; ++j) {
    int h = lane + 64 * j;
    float bqv = bq[h], bkv = bk[h], bcv = bc1[h];
    #pragma unroll
    for (int r = 0; r < 4; ++r) { qv[r][j] = bqv; kv[r][j] = bkv; cv[r][j] = bcv; }
  }
  for (int d2 = 0; d2 < 64; ++d2) {
    float hv0 = hcs[wid][0][d2], hv1 = hcs[wid][1][d2];
    float hv2 = hcs[wid][2][d2], hv3 = hcs[wid][3][d2];
    #pragma unroll
    for (int j = 0; j < 4; ++j) {
      int h = lane + 64 * j;
      float wq = WqT[d2 * 256 + h], wk = WkT[d2 * 256 + h], wc = Wc1T[d2 * 256 + h];
      qv[0][j] = fmaf(wq, hv0, qv[0][j]); qv[1][j] = fmaf(wq, hv1, qv[1][j]);
      qv[2][j] = fmaf(wq, hv2, qv[2][j]); qv[3][j] = fmaf(wq, hv3, qv[3][j]);
      kv[0][j] = fmaf(wk, hv0, kv[0][j]); kv[1][j] = fmaf(wk, hv1, kv[1][j]);
      kv[2][j] = fmaf(wk, hv2, kv[2][j]); kv[3][j] = fmaf(wk, hv3, kv[3][j]);
      cv[0][j] = fmaf(wc, hv0, cv[0][j]); cv[1][j] = fmaf(wc, hv1, cv[1][j]);
      cv[2][j] = fmaf(wc, hv2, cv[2][j]); cv[3][j] = fmaf(wc, hv3, cv[3][j]);
    }
  }
  #pragma unroll
  for (int r = 0; r < 4; ++r)
    #pragma unroll
    for (int j = 0; j < 4; ++j)
      ts[wid][r][lane + 64 * j] = tanhf(qv[r][j] * kv[r][j]);
  __syncthreads();

  float sc[4];
  { float b = bs[lane]; sc[0] = b; sc[1] = b; sc[2] = b; sc[3] = b; }
  for (int h2 = 0; h2 < 256; ++h2) {
    float w = WsT[h2 * 64 + lane];
    sc[0] = fmaf(w, ts[wid][0][h2], sc[0]);
    sc[1] = fmaf(w, ts[wid][1][h2], sc[1]);
    sc[2] = fmaf(w, ts[wid][2][h2], sc[2]);
    sc[3] = fmaf(w, ts[wid][3][h2], sc[3]);
  }

  float hcr[4] = {hc4.x, hc4.y, hc4.z, hc4.w};
  float res[4];
  #pragma unroll
  for (int r = 0; r < 4; ++r) {
    float s = sc[r];
    float mx = s;
    #pragma unroll
    for (int off = 1; off < 64; off <<= 1) mx = fmaxf(mx, __shfl_xor(mx, off));
    float e = __expf(s - mx);
    float se = e;
    #pragma unroll
    for (int off = 1; off < 64; off <<= 1) se += __shfl_xor(se, off);
    float wgt = hcr[r] * (e / se);
    #pragma unroll
    for (int off = 1; off < 64; off <<= 1) wgt += __shfl_xor(wgt, off);
    float cp = 0.f;
    #pragma unroll
    for (int j = 0; j < 4; ++j) cp = fmaf(fmaxf(cv[r][j], 0.f), Wc2[lane + 64 * j], cp);
    #pragma unroll
    for (int off = 1; off < 64; off <<= 1) cp += __shfl_xor(cp, off);
    float comb = wgt + cp + bc2[0];
    float fp = 0.f;
    #pragma unroll
    for (int j = 0; j < 4; ++j) {
      int h = lane + 64 * j;
      fp = fmaf(fmaxf(fmaf(comb, Wg1[h], bg1[h]), 0.f), Wg2[h], fp);
    }
    #pragma unroll
    for (int off = 1; off < 64; off <<= 1) fp += __shfl_xor(fp, off);
    res[r] = fp + bg2[0];
  }
  if (lane == 0) {
    float4 o = make_float4(res[0], res[1], res[2], res[3]);
    *(float4*)(out + r0) = o;
  }
}

extern "C" void kernel_launch(void* const* d_in, const int* in_sizes, int n_in,
                              void* d_out, int out_size, void* d_ws, size_t ws_size,
                              hipStream_t stream) {
  const float* x   = (const float*)d_in[0];
  const float* W1  = (const float*)d_in[1];
  const float* b1  = (const float*)d_in[2];
  const float* W2  = (const float*)d_in[3];
  const float* b2  = (const float*)d_in[4];
  const float* W3  = (const float*)d_in[5];
  const float* b3  = (const float*)d_in[6];
  const float* Wq  = (const float*)d_in[7];
  const float* bq  = (const float*)d_in[8];
  const float* Wk  = (const float*)d_in[9];
  const float* bk  = (const float*)d_in[10];
  const float* Ws  = (const float*)d_in[11];
  const float* bs  = (const float*)d_in[12];
  const float* Wc1 = (const float*)d_in[13];
  const float* bc1 = (const float*)d_in[14];
  const float* Wc2 = (const float*)d_in[15];
  const float* bc2 = (const float*)d_in[16];
  const float* Wg1 = (const float*)d_in[17];
  const float* bg1 = (const float*)d_in[18];
  const float* Wg2 = (const float*)d_in[19];
  const float* bg2 = (const float*)d_in[20];

  unsigned short* Bp = (unsigned short*)d_ws;               // 8,388,608 B
  float* hcT  = (float*)((char*)d_ws + 8388608);            // 4,194,304 B
  float* WqT  = (float*)((char*)d_ws + 12582912);
  float* WkT  = WqT + 16384;
  float* Wc1T = WkT + 16384;
  float* WsT  = Wc1T + 16384;

  pack_w2<<<2048, 256, 0, stream>>>(W2, Bp);
  prep_t<<<64, 256, 0, stream>>>(Wq, Wk, Wc1, Ws, WqT, WkT, Wc1T, WsT);
  gemm_hcat<<<512, 512, 0, stream>>>(x, W1, b1, b2, W3, b3, Bp, hcT);
  fused_tail<<<1024, 256, 0, stream>>>(hcT, WqT, bq, WkT, bk, WsT, bs, Wc1T, bc1,
                                       Wc2, bc2, Wg1, bg1, Wg2, bg2, (float*)d_out);
}

// Round 13
// 243.894 us; speedup vs baseline: 2.3898x; 1.1115x over previous
//
#include <hip/hip_runtime.h>
#include <stdint.h>

#define Bn 16384
#define Dn 64
#define Hn 256

typedef short bf16x8 __attribute__((ext_vector_type(8)));
typedef float f32x4 __attribute__((ext_vector_type(4)));

__device__ __forceinline__ unsigned f2bf1(float f) {
  unsigned u = __float_as_uint(f);
  return (u + 0x7FFFu + ((u >> 16) & 1u)) >> 16;   // RNE to bf16
}

// ---------- pack W2 (fp32 [D][H][H]) into MFMA B-fragment-linear bf16 ----------
// layout: [d][kk(8)][nj(16)][lane(64)][8 bf16]; lane holds B[k=kk*32+(lane>>4)*8+b][n=nj*16+(lane&15)]
__global__ __launch_bounds__(256) void pack_w2(const float* __restrict__ W2,
                                               unsigned short* __restrict__ Bp) {
  int g = blockIdx.x * 4 + (threadIdx.x >> 6);   // 8192 units
  int lane = threadIdx.x & 63;
  int d  = g >> 7;
  int kk = (g >> 4) & 7;
  int nj = g & 15;
  int k0 = kk * 32 + ((lane >> 4) << 3);
  int n  = nj * 16 + (lane & 15);
  const float* src = W2 + ((size_t)d * Hn + k0) * Hn + n;
  unsigned t[8];
  #pragma unroll
  for (int b = 0; b < 8; ++b) t[b] = f2bf1(src[(size_t)b * Hn]);
  uint4 w;
  w.x = t[0] | (t[1] << 16);
  w.y = t[2] | (t[3] << 16);
  w.z = t[4] | (t[5] << 16);
  w.w = t[6] | (t[7] << 16);
  size_t off = (((size_t)g) * 64 + lane) * 8;    // elements
  *(uint4*)(Bp + off) = w;
}

// ---------- transpose small tail weights for coalesced reads ----------
__global__ __launch_bounds__(256) void prep_t(
    const float* __restrict__ Wq, const float* __restrict__ Wk,
    const float* __restrict__ Wc1, const float* __restrict__ Ws,
    float* __restrict__ WqT, float* __restrict__ WkT,
    float* __restrict__ Wc1T, float* __restrict__ WsT) {
  int t = blockIdx.x * 256 + threadIdx.x;   // 16384
  int h = t >> 6, dd = t & 63;
  WqT[dd * 256 + h]  = Wq[h * 64 + dd];
  WkT[dd * 256 + h]  = Wk[h * 64 + dd];
  Wc1T[dd * 256 + h] = Wc1[h * 64 + dd];
  WsT[h * 64 + dd]   = Ws[dd * 256 + h];
}

// ---------- persistent fused GEMM: 1M x 8N, all-persistent registers ----------
// 512 blocks = 8 xcd x 8 dlocal x 8 chunks (2/CU, ALL co-resident).
// 512 threads = 8 waves 1M x 8N: wave = 32 rows x 32 cols; T=64 tiles of 32
// rows per block. Persistent per wave: breg[16] (its 32 cols x K=256, 64
// VGPR, gathered once from packed Bp) + W1/b1 k-slice (16 VGPR). a1 via
// 2x16KB LDS dbuf: wave w computes stage w of tile t+1 inside tile t's
// K-loop. Swapped-operand MFMA -> rows at l15, 2-shfl epilogue; b2 in acc
// init. NOTE: __launch_bounds__ 2nd arg acts as CUDA-style MIN BLOCKS/CU in
// hipcc (R7-R12 evidence): (512,2) -> 16 waves/CU -> 128 arch-VGPR cap,
// demand ~105 -> NO SPILL. (512,4) forced a 64-reg cap and spilled.
__global__ __launch_bounds__(512, 2) void gemm_hcat(
    const float* __restrict__ x, const float* __restrict__ W1,
    const float* __restrict__ b1, const float* __restrict__ b2,
    const float* __restrict__ W3, const float* __restrict__ b3,
    const unsigned short* __restrict__ Bp, float* __restrict__ hcT) {
  __shared__ char As[2][16384];   // [slot(16)=s*2+gm][lane(64)][16B]
  __shared__ float P[2][8][32];

  int bid = blockIdx.x;
  int xcd = bid & 7;
  int dl = (bid >> 3) & 7;
  int chunk = bid >> 6;            // 0..7
  int d = xcd * 8 + dl;            // 8 d per XCD -> Bp slice + x lines L2-hot
  int base = chunk * 2048;         // 64 tiles of 32 rows

  int tid = threadIdx.x;
  int lane = tid & 63;
  int w = tid >> 6;                // wave id = wn; owns cols w*32.., a1 stage w
  int l15 = lane & 15;
  int g = lane >> 4;

  const unsigned short* BpD = Bp + (size_t)d * 65536;
  const float* b2d = b2 + d * Hn;
  const float* W3d = W3 + d * Hn;
  float b3d = b3[d];

  // persistent W1/b1 k-slice: this thread always handles k = w*32 + g*8 + (0..7)
  int k0 = w * 32 + (g << 3);
  float4 w1a = *(const float4*)(W1 + d * Hn + k0);
  float4 w1b = *(const float4*)(W1 + d * Hn + k0 + 4);
  float4 b1a = *(const float4*)(b1 + d * Hn + k0);
  float4 b1b = *(const float4*)(b1 + d * Hn + k0 + 4);

  // persistent breg[16]: this wave's 32 cols (nj = 2w, 2w+1) x full K
  bf16x8 breg[16];
  #pragma unroll
  for (int s = 0; s < 8; ++s)
    #pragma unroll
    for (int j = 0; j < 2; ++j)
      breg[s * 2 + j] = *(const bf16x8*)(BpD + (((s * 16 + 2 * w + j) << 6) + lane) * 8);

  // a1 slot (stage=w, row-group gm): row = gm*16+l15, k = w*32+g*8+(0..7)
  #define A1SLOT(wbuf, gm, xv)                                                  \
    {                                                                           \
      float v0 = fmaxf(fmaf((xv), w1a.x, b1a.x), 0.f);                          \
      float v1 = fmaxf(fmaf((xv), w1a.y, b1a.y), 0.f);                          \
      float v2 = fmaxf(fmaf((xv), w1a.z, b1a.z), 0.f);                          \
      float v3 = fmaxf(fmaf((xv), w1a.w, b1a.w), 0.f);                          \
      float v4 = fmaxf(fmaf((xv), w1b.x, b1b.x), 0.f);                          \
      float v5 = fmaxf(fmaf((xv), w1b.y, b1b.y), 0.f);                          \
      float v6 = fmaxf(fmaf((xv), w1b.z, b1b.z), 0.f);                          \
      float v7 = fmaxf(fmaf((xv), w1b.w, b1b.w), 0.f);                          \
      uint4 pk;                                                                 \
      asm("v_cvt_pk_bf16_f32 %0, %1, %2" : "=v"(pk.x) : "v"(v0), "v"(v1));      \
      asm("v_cvt_pk_bf16_f32 %0, %1, %2" : "=v"(pk.y) : "v"(v2), "v"(v3));      \
      asm("v_cvt_pk_bf16_f32 %0, %1, %2" : "=v"(pk.z) : "v"(v4), "v"(v5));      \
      asm("v_cvt_pk_bf16_f32 %0, %1, %2" : "=v"(pk.w) : "v"(v6), "v"(v7));      \
      *(uint4*)((wbuf) + (((w << 1) + (gm)) << 10) + (lane << 4)) = pk;         \
    }

  // prologue: a1 for tile 0
  {
    float x0 = x[(size_t)(base + l15) * Dn + d];
    float x1 = x[(size_t)(base + 16 + l15) * Dn + d];
    A1SLOT(As[0], 0, x0);
    A1SLOT(As[0], 1, x1);
  }
  __syncthreads();

  for (int t = 0; t < 64; ++t) {
    int p = t & 1;
    const char* rb = As[p];
    char* wbuf = As[p ^ 1];
    bool pre = (t < 63);
    float xn0 = 0.f, xn1 = 0.f;
    if (pre) {
      xn0 = x[(size_t)(base + (t + 1) * 32 + l15) * Dn + d];
      xn1 = x[(size_t)(base + (t + 1) * 32 + 16 + l15) * Dn + d];
    }

    // acc init = b2 (folded); col = w*32 + nj*16 + g*4 + i
    f32x4 acc[2][2];
    {
      float4 bv0 = *(const float4*)(b2d + (w << 5) + (g << 2));
      float4 bv1 = *(const float4*)(b2d + (w << 5) + 16 + (g << 2));
      f32x4 i0 = {bv0.x, bv0.y, bv0.z, bv0.w};
      f32x4 i1 = {bv1.x, bv1.y, bv1.z, bv1.w};
      acc[0][0] = i0; acc[1][0] = i0;
      acc[0][1] = i1; acc[1][1] = i1;
    }

    #pragma unroll
    for (int s = 0; s < 8; ++s) {
      bf16x8 af0 = *(const bf16x8*)(rb + ((s << 1) << 10) + (lane << 4));
      bf16x8 af1 = *(const bf16x8*)(rb + (((s << 1) + 1) << 10) + (lane << 4));
      if (pre && s == 2) { A1SLOT(wbuf, 0, xn0); }
      if (pre && s == 5) { A1SLOT(wbuf, 1, xn1); }
      __builtin_amdgcn_s_setprio(1);
      acc[0][0] = __builtin_amdgcn_mfma_f32_16x16x32_bf16(breg[s * 2 + 0], af0, acc[0][0], 0, 0, 0);
      acc[1][0] = __builtin_amdgcn_mfma_f32_16x16x32_bf16(breg[s * 2 + 0], af1, acc[1][0], 0, 0, 0);
      acc[0][1] = __builtin_amdgcn_mfma_f32_16x16x32_bf16(breg[s * 2 + 1], af0, acc[0][1], 0, 0, 0);
      acc[1][1] = __builtin_amdgcn_mfma_f32_16x16x32_bf16(breg[s * 2 + 1], af1, acc[1][1], 0, 0, 0);
      __builtin_amdgcn_s_setprio(0);
    }

    // epilogue: relu . W3 over this wave's 32 cols; rows at l15, 2 shfls
    {
      float4 wv0 = *(const float4*)(W3d + (w << 5) + (g << 2));
      float4 wv1 = *(const float4*)(W3d + (w << 5) + 16 + (g << 2));
      #pragma unroll
      for (int mi = 0; mi < 2; ++mi) {
        float ph;
        ph = fmaxf(acc[mi][0][0], 0.f) * wv0.x;
        ph = fmaf(fmaxf(acc[mi][0][1], 0.f), wv0.y, ph);
        ph = fmaf(fmaxf(acc[mi][0][2], 0.f), wv0.z, ph);
        ph = fmaf(fmaxf(acc[mi][0][3], 0.f), wv0.w, ph);
        ph = fmaf(fmaxf(acc[mi][1][0], 0.f), wv1.x, ph);
        ph = fmaf(fmaxf(acc[mi][1][1], 0.f), wv1.y, ph);
        ph = fmaf(fmaxf(acc[mi][1][2], 0.f), wv1.z, ph);
        ph = fmaf(fmaxf(acc[mi][1][3], 0.f), wv1.w, ph);
        ph += __shfl_xor(ph, 16);
        ph += __shfl_xor(ph, 32);
        if (lane < 16) P[p][w][(mi << 4) + l15] = ph;
      }
    }
    __syncthreads();   // a1(t+1) written + P(t) visible
    if (tid < 32) {
      const float* pp = &P[p][0][tid];
      float h = ((pp[0] + pp[32]) + (pp[64] + pp[96])) +
                ((pp[128] + pp[160]) + (pp[192] + pp[224])) + b3d;
      hcT[(size_t)d * Bn + base + t * 32 + tid] = h;
    }
  }
  #undef A1SLOT
}

// ---------- tail: attention fusion + cross MLP + g_func; 4 rows per wave ----------
__global__ __launch_bounds__(256) void fused_tail(
    const float* __restrict__ hcT, const float* __restrict__ WqT,
    const float* __restrict__ bq, const float* __restrict__ WkT,
    const float* __restrict__ bk, const float* __restrict__ WsT,
    const float* __restrict__ bs, const float* __restrict__ Wc1T,
    const float* __restrict__ bc1, const float* __restrict__ Wc2,
    const float* __restrict__ bc2, const float* __restrict__ Wg1,
    const float* __restrict__ bg1, const float* __restrict__ Wg2,
    const float* __restrict__ bg2, float* __restrict__ out) {
  __shared__ float hcs[4][4][64];
  __shared__ float ts[4][4][256];
  int wid = threadIdx.x >> 6;
  int lane = threadIdx.x & 63;
  int r0 = (blockIdx.x * 4 + wid) * 4;                 // 4 rows per wave
  float4 hc4 = *(const float4*)(hcT + (size_t)lane * Bn + r0);   // lane <-> feature d
  hcs[wid][0][lane] = hc4.x;
  hcs[wid][1][lane] = hc4.y;
  hcs[wid][2][lane] = hc4.z;
  hcs[wid][3][lane] = hc4.w;
  __syncthreads();

  float qv[4][4], kv[4][4], cv[4][4];
  #pragma unroll
  for (int j = 0; j < 4; ++j) {
    int h = lane + 64 * j;
    float bqv = bq[h], bkv = bk[h], bcv = bc1[h];
    #pragma unroll
    for (int r = 0; r < 4; ++r) { qv[r][j] = bqv; kv[r][j] = bkv; cv[r][j] = bcv; }
  }
  for (int d2 = 0; d2 < 64; ++d2) {
    float hv0 = hcs[wid][0][d2], hv1 = hcs[wid][1][d2];
    float hv2 = hcs[wid][2][d2], hv3 = hcs[wid][3][d2];
    #pragma unroll
    for (int j = 0; j < 4; ++j) {
      int h = lane + 64 * j;
      float wq = WqT[d2 * 256 + h], wk = WkT[d2 * 256 + h], wc = Wc1T[d2 * 256 + h];
      qv[0][j] = fmaf(wq, hv0, qv[0][j]); qv[1][j] = fmaf(wq, hv1, qv[1][j]);
      qv[2][j] = fmaf(wq, hv2, qv[2][j]); qv[3][j] = fmaf(wq, hv3, qv[3][j]);
      kv[0][j] = fmaf(wk, hv0, kv[0][j]); kv[1][j] = fmaf(wk, hv1, kv[1][j]);
      kv[2][j] = fmaf(wk, hv2, kv[2][j]); kv[3][j] = fmaf(wk, hv3, kv[3][j]);
      cv[0][j] = fmaf(wc, hv0, cv[0][j]); cv[1][j] = fmaf(wc, hv1, cv[1][j]);
      cv[2][j] = fmaf(wc, hv2, cv[2][j]); cv[3][j] = fmaf(wc, hv3, cv[3][j]);
    }
  }
  #pragma unroll
  for (int r = 0; r < 4; ++r)
    #pragma unroll
    for (int j = 0; j < 4; ++j)
      ts[wid][r][lane + 64 * j] = tanhf(qv[r][j] * kv[r][j]);
  __syncthreads();

  float sc[4];
  { float b = bs[lane]; sc[0] = b; sc[1] = b; sc[2] = b; sc[3] = b; }
  for (int h2 = 0; h2 < 256; ++h2) {
    float w = WsT[h2 * 64 + lane];
    sc[0] = fmaf(w, ts[wid][0][h2], sc[0]);
    sc[1] = fmaf(w, ts[wid][1][h2], sc[1]);
    sc[2] = fmaf(w, ts[wid][2][h2], sc[2]);
    sc[3] = fmaf(w, ts[wid][3][h2], sc[3]);
  }

  float hcr[4] = {hc4.x, hc4.y, hc4.z, hc4.w};
  float res[4];
  #pragma unroll
  for (int r = 0; r < 4; ++r) {
    float s = sc[r];
    float mx = s;
    #pragma unroll
    for (int off = 1; off < 64; off <<= 1) mx = fmaxf(mx, __shfl_xor(mx, off));
    float e = __expf(s - mx);
    float se = e;
    #pragma unroll
    for (int off = 1; off < 64; off <<= 1) se += __shfl_xor(se, off);
    float wgt = hcr[r] * (e / se);
    #pragma unroll
    for (int off = 1; off < 64; off <<= 1) wgt += __shfl_xor(wgt, off);
    float cp = 0.f;
    #pragma unroll
    for (int j = 0; j < 4; ++j) cp = fmaf(fmaxf(cv[r][j], 0.f), Wc2[lane + 64 * j], cp);
    #pragma unroll
    for (int off = 1; off < 64; off <<= 1) cp += __shfl_xor(cp, off);
    float comb = wgt + cp + bc2[0];
    float fp = 0.f;
    #pragma unroll
    for (int j = 0; j < 4; ++j) {
      int h = lane + 64 * j;
      fp = fmaf(fmaxf(fmaf(comb, Wg1[h], bg1[h]), 0.f), Wg2[h], fp);
    }
    #pragma unroll
    for (int off = 1; off < 64; off <<= 1) fp += __shfl_xor(fp, off);
    res[r] = fp + bg2[0];
  }
  if (lane == 0) {
    float4 o = make_float4(res[0], res[1], res[2], res[3]);
    *(float4*)(out + r0) = o;
  }
}

extern "C" void kernel_launch(void* const* d_in, const int* in_sizes, int n_in,
                              void* d_out, int out_size, void* d_ws, size_t ws_size,
                              hipStream_t stream) {
  const float* x   = (const float*)d_in[0];
  const float* W1  = (const float*)d_in[1];
  const float* b1  = (const float*)d_in[2];
  const float* W2  = (const float*)d_in[3];
  const float* b2  = (const float*)d_in[4];
  const float* W3  = (const float*)d_in[5];
  const float* b3  = (const float*)d_in[6];
  const float* Wq  = (const float*)d_in[7];
  const float* bq  = (const float*)d_in[8];
  const float* Wk  = (const float*)d_in[9];
  const float* bk  = (const float*)d_in[10];
  const float* Ws  = (const float*)d_in[11];
  const float* bs  = (const float*)d_in[12];
  const float* Wc1 = (const float*)d_in[13];
  const float* bc1 = (const float*)d_in[14];
  const float* Wc2 = (const float*)d_in[15];
  const float* bc2 = (const float*)d_in[16];
  const float* Wg1 = (const float*)d_in[17];
  const float* bg1 = (const float*)d_in[18];
  const float* Wg2 = (const float*)d_in[19];
  const float* bg2 = (const float*)d_in[20];

  unsigned short* Bp = (unsigned short*)d_ws;               // 8,388,608 B
  float* hcT  = (float*)((char*)d_ws + 8388608);            // 4,194,304 B
  float* WqT  = (float*)((char*)d_ws + 12582912);
  float* WkT  = WqT + 16384;
  float* Wc1T = WkT + 16384;
  float* WsT  = Wc1T + 16384;

  pack_w2<<<2048, 256, 0, stream>>>(W2, Bp);
  prep_t<<<64, 256, 0, stream>>>(Wq, Wk, Wc1, Ws, WqT, WkT, Wc1T, WsT);
  gemm_hcat<<<512, 512, 0, stream>>>(x, W1, b1, b2, W3, b3, Bp, hcT);
  fused_tail<<<1024, 256, 0, stream>>>(hcT, WqT, bq, WkT, bk, WsT, bs, Wc1T, bc1,
                                       Wc2, bc2, Wg1, bg1, Wg2, bg2, (float*)d_out);
}

// Round 14
// 182.439 us; speedup vs baseline: 3.1948x; 1.3369x over previous
//
#include <hip/hip_runtime.h>
#include <stdint.h>

#define Bn 16384
#define Dn 64
#define Hn 256

typedef short bf16x8 __attribute__((ext_vector_type(8)));
typedef float f32x4 __attribute__((ext_vector_type(4)));

__device__ __forceinline__ unsigned f2bf1(float f) {
  unsigned u = __float_as_uint(f);
  return (u + 0x7FFFu + ((u >> 16) & 1u)) >> 16;   // RNE to bf16
}

// ---------- pack W2 (fp32 [D][H][H]) into MFMA B-fragment-linear bf16 ----------
// layout: [d][kk(8)][nj(16)][lane(64)][8 bf16]; lane holds B[k=kk*32+(lane>>4)*8+b][n=nj*16+(lane&15)]
__global__ __launch_bounds__(256) void pack_w2(const float* __restrict__ W2,
                                               unsigned short* __restrict__ Bp) {
  int g = blockIdx.x * 4 + (threadIdx.x >> 6);   // 8192 units
  int lane = threadIdx.x & 63;
  int d  = g >> 7;
  int kk = (g >> 4) & 7;
  int nj = g & 15;
  int k0 = kk * 32 + ((lane >> 4) << 3);
  int n  = nj * 16 + (lane & 15);
  const float* src = W2 + ((size_t)d * Hn + k0) * Hn + n;
  unsigned t[8];
  #pragma unroll
  for (int b = 0; b < 8; ++b) t[b] = f2bf1(src[(size_t)b * Hn]);
  uint4 w;
  w.x = t[0] | (t[1] << 16);
  w.y = t[2] | (t[3] << 16);
  w.z = t[4] | (t[5] << 16);
  w.w = t[6] | (t[7] << 16);
  size_t off = (((size_t)g) * 64 + lane) * 8;    // elements
  *(uint4*)(Bp + off) = w;
}

// ---------- transpose small tail weights for coalesced reads ----------
__global__ __launch_bounds__(256) void prep_t(
    const float* __restrict__ Wq, const float* __restrict__ Wk,
    const float* __restrict__ Wc1, const float* __restrict__ Ws,
    float* __restrict__ WqT, float* __restrict__ WkT,
    float* __restrict__ Wc1T, float* __restrict__ WsT) {
  int t = blockIdx.x * 256 + threadIdx.x;   // 16384
  int h = t >> 6, dd = t & 63;
  WqT[dd * 256 + h]  = Wq[h * 64 + dd];
  WkT[dd * 256 + h]  = Wk[h * 64 + dd];
  Wc1T[dd * 256 + h] = Wc1[h * 64 + dd];
  WsT[h * 64 + dd]   = Ws[dd * 256 + h];
}

// ---------- fused GEMM: 4-wave blocks (2/CU, de-phased barriers), c=64 waves ----
// 1024 blocks = 8 xcd x 8 dlocal x 16 chunks; 256 threads = 4 waves 1M x 4N:
// wave = 32 rows x 64 cols (matrix-dominant MFMA:LDS ratio), 32 tiles of 32
// rows per block. Per wave persistent: breg[32] (its 64 cols x K=256, 128
// VGPR, gathered once from packed Bp) + W1/b1 slice for stage 2w (16 regs);
// stage 2w+1 weights JIT (short liveness). a1 via 2x16KB LDS dbuf, wave w
// owns stages {2w,2w+1}, interleaved into the K-loop; ONE barrier per tile.
// Two 4-wave blocks per CU de-phase their barriers -> MFMA of one overlaps
// VALU of the other (R6's serialized-pipes diagnosis). Swapped-operand MFMA
// -> rows at l15, 2-shfl epilogue; b2 folded into acc init.
__global__ __launch_bounds__(256, 2) void gemm_hcat(
    const float* __restrict__ x, const float* __restrict__ W1,
    const float* __restrict__ b1, const float* __restrict__ b2,
    const float* __restrict__ W3, const float* __restrict__ b3,
    const unsigned short* __restrict__ Bp, float* __restrict__ hcT) {
  __shared__ char As[2][16384];   // [slot(16)=st*2+gm][lane(64)][16B]
  __shared__ float P[2][4][32];

  int bid = blockIdx.x;
  int xcd = bid & 7;
  int dl = (bid >> 3) & 7;
  int chunk = bid >> 6;            // 0..15
  int d = xcd * 8 + dl;            // 8 d per XCD -> Bp slice + x lines L2-hot
  int base = chunk * 1024;         // 32 tiles of 32 rows

  int tid = threadIdx.x;
  int lane = tid & 63;
  int w = tid >> 6;                // wave id = wn (cols w*64..); a1 stages {2w,2w+1}
  int l15 = lane & 15;
  int g = lane >> 4;

  const unsigned short* BpD = Bp + (size_t)d * 65536;
  const float* W1d = W1 + d * Hn;
  const float* b1d = b1 + d * Hn;
  const float* b2d = b2 + d * Hn;
  const float* W3d = W3 + d * Hn;
  float b3d = b3[d];

  // persistent W1/b1 slice for stage 2w: k = 2w*32 + g*8 + (0..7)
  int ka = (w << 6) + (g << 3);
  float4 w1a = *(const float4*)(W1d + ka);
  float4 w1b = *(const float4*)(W1d + ka + 4);
  float4 b1a = *(const float4*)(b1d + ka);
  float4 b1b = *(const float4*)(b1d + ka + 4);

  // persistent breg[32]: this wave's 64 cols (nj = 4w..4w+3) x full K
  bf16x8 breg[32];
  #pragma unroll
  for (int s = 0; s < 8; ++s)
    #pragma unroll
    for (int nj = 0; nj < 4; ++nj)
      breg[s * 4 + nj] = *(const bf16x8*)(BpD + (((s * 16 + (w << 2) + nj) << 6) + lane) * 8);

  // a1 slot writer: slot (st, gm) at offset (st*2+gm)*1024; k-octet from WA/WB/BA/BB
  #define A1SLOT(wbuf, st, gm, xv, WA, WB, BA, BB)                              \
    {                                                                           \
      float v0 = fmaxf(fmaf((xv), WA.x, BA.x), 0.f);                            \
      float v1 = fmaxf(fmaf((xv), WA.y, BA.y), 0.f);                            \
      float v2 = fmaxf(fmaf((xv), WA.z, BA.z), 0.f);                            \
      float v3 = fmaxf(fmaf((xv), WA.w, BA.w), 0.f);                            \
      float v4 = fmaxf(fmaf((xv), WB.x, BB.x), 0.f);                            \
      float v5 = fmaxf(fmaf((xv), WB.y, BB.y), 0.f);                            \
      float v6 = fmaxf(fmaf((xv), WB.z, BB.z), 0.f);                            \
      float v7 = fmaxf(fmaf((xv), WB.w, BB.w), 0.f);                            \
      uint4 pk;                                                                 \
      asm("v_cvt_pk_bf16_f32 %0, %1, %2" : "=v"(pk.x) : "v"(v0), "v"(v1));      \
      asm("v_cvt_pk_bf16_f32 %0, %1, %2" : "=v"(pk.y) : "v"(v2), "v"(v3));      \
      asm("v_cvt_pk_bf16_f32 %0, %1, %2" : "=v"(pk.z) : "v"(v4), "v"(v5));      \
      asm("v_cvt_pk_bf16_f32 %0, %1, %2" : "=v"(pk.w) : "v"(v6), "v"(v7));      \
      *(uint4*)((wbuf) + ((((st) << 1) + (gm)) << 10) + (lane << 4)) = pk;      \
    }

  // JIT variant for stage 2w+1 (loads L1-hot, liveness ~10 instr)
  #define A1SLOTJ(wbuf, gm, xv)                                                 \
    {                                                                           \
      int kc = (w << 6) + 32 + (g << 3);                                        \
      float4 wc0 = *(const float4*)(W1d + kc);                                  \
      float4 wc1 = *(const float4*)(W1d + kc + 4);                              \
      float4 bc0 = *(const float4*)(b1d + kc);                                  \
      float4 bc1 = *(const float4*)(b1d + kc + 4);                              \
      A1SLOT(wbuf, 2 * w + 1, gm, xv, wc0, wc1, bc0, bc1);                      \
    }

  // prologue: a1 for tile 0 (this wave's two stages, both row-groups)
  {
    float x0 = x[(size_t)(base + l15) * Dn + d];
    float x1 = x[(size_t)(base + 16 + l15) * Dn + d];
    A1SLOT(As[0], 2 * w, 0, x0, w1a, w1b, b1a, b1b);
    A1SLOT(As[0], 2 * w, 1, x1, w1a, w1b, b1a, b1b);
    A1SLOTJ(As[0], 0, x0);
    A1SLOTJ(As[0], 1, x1);
  }
  __syncthreads();

  for (int t = 0; t < 32; ++t) {
    int p = t & 1;
    const char* rb = As[p];
    char* wb = As[p ^ 1];
    bool pre = (t < 31);
    float xn0 = 0.f, xn1 = 0.f;
    if (pre) {
      xn0 = x[(size_t)(base + (t + 1) * 32 + l15) * Dn + d];
      xn1 = x[(size_t)(base + (t + 1) * 32 + 16 + l15) * Dn + d];
    }

    // acc init = b2 (folded); col = w*64 + nj*16 + g*4 + i
    f32x4 acc[2][4];
    #pragma unroll
    for (int nj = 0; nj < 4; ++nj) {
      float4 bv = *(const float4*)(b2d + (w << 6) + (nj << 4) + (g << 2));
      f32x4 iv = {bv.x, bv.y, bv.z, bv.w};
      acc[0][nj] = iv;
      acc[1][nj] = iv;
    }

    #pragma unroll
    for (int s = 0; s < 8; ++s) {
      bf16x8 af0 = *(const bf16x8*)(rb + ((s << 1) << 10) + (lane << 4));
      bf16x8 af1 = *(const bf16x8*)(rb + (((s << 1) + 1) << 10) + (lane << 4));
      if (pre && s == 1) { A1SLOT(wb, 2 * w, 0, xn0, w1a, w1b, b1a, b1b); }
      if (pre && s == 3) { A1SLOT(wb, 2 * w, 1, xn1, w1a, w1b, b1a, b1b); }
      if (pre && s == 5) { A1SLOTJ(wb, 0, xn0); }
      if (pre && s == 7) { A1SLOTJ(wb, 1, xn1); }
      __builtin_amdgcn_s_setprio(1);
      #pragma unroll
      for (int nj = 0; nj < 4; ++nj) {
        acc[0][nj] = __builtin_amdgcn_mfma_f32_16x16x32_bf16(breg[s * 4 + nj], af0, acc[0][nj], 0, 0, 0);
        acc[1][nj] = __builtin_amdgcn_mfma_f32_16x16x32_bf16(breg[s * 4 + nj], af1, acc[1][nj], 0, 0, 0);
      }
      __builtin_amdgcn_s_setprio(0);
    }

    // epilogue: relu . W3 over this wave's 64 cols; rows at l15, 2 shfls
    {
      float4 wv[4];
      #pragma unroll
      for (int nj = 0; nj < 4; ++nj)
        wv[nj] = *(const float4*)(W3d + (w << 6) + (nj << 4) + (g << 2));
      #pragma unroll
      for (int mi = 0; mi < 2; ++mi) {
        float ph = 0.f;
        #pragma unroll
        for (int nj = 0; nj < 4; ++nj) {
          ph = fmaf(fmaxf(acc[mi][nj][0], 0.f), wv[nj].x, ph);
          ph = fmaf(fmaxf(acc[mi][nj][1], 0.f), wv[nj].y, ph);
          ph = fmaf(fmaxf(acc[mi][nj][2], 0.f), wv[nj].z, ph);
          ph = fmaf(fmaxf(acc[mi][nj][3], 0.f), wv[nj].w, ph);
        }
        ph += __shfl_xor(ph, 16);
        ph += __shfl_xor(ph, 32);
        if (lane < 16) P[p][w][(mi << 4) + l15] = ph;
      }
    }
    __syncthreads();   // a1(t+1) written + P(t) visible
    if (tid < 32) {
      float h = P[p][0][tid] + P[p][1][tid] + P[p][2][tid] + P[p][3][tid] + b3d;
      hcT[(size_t)d * Bn + base + t * 32 + tid] = h;
    }
  }
  #undef A1SLOTJ
  #undef A1SLOT
}

// ---------- tail: attention fusion + cross MLP + g_func; 4 rows per wave ----------
__global__ __launch_bounds__(256) void fused_tail(
    const float* __restrict__ hcT, const float* __restrict__ WqT,
    const float* __restrict__ bq, const float* __restrict__ WkT,
    const float* __restrict__ bk, const float* __restrict__ WsT,
    const float* __restrict__ bs, const float* __restrict__ Wc1T,
    const float* __restrict__ bc1, const float* __restrict__ Wc2,
    const float* __restrict__ bc2, const float* __restrict__ Wg1,
    const float* __restrict__ bg1, const float* __restrict__ Wg2,
    const float* __restrict__ bg2, float* __restrict__ out) {
  __shared__ float hcs[4][4][64];
  __shared__ float ts[4][4][256];
  int wid = threadIdx.x >> 6;
  int lane = threadIdx.x & 63;
  int r0 = (blockIdx.x * 4 + wid) * 4;                 // 4 rows per wave
  float4 hc4 = *(const float4*)(hcT + (size_t)lane * Bn + r0);   // lane <-> feature d
  hcs[wid][0][lane] = hc4.x;
  hcs[wid][1][lane] = hc4.y;
  hcs[wid][2][lane] = hc4.z;
  hcs[wid][3][lane] = hc4.w;
  __syncthreads();

  float qv[4][4], kv[4][4], cv[4][4];
  #pragma unroll
  for (int j = 0; j < 4; ++j) {
    int h = lane + 64 * j;
    float bqv = bq[h], bkv = bk[h], bcv = bc1[h];
    #pragma unroll
    for (int r = 0; r < 4; ++r) { qv[r][j] = bqv; kv[r][j] = bkv; cv[r][j] = bcv; }
  }
  for (int d2 = 0; d2 < 64; ++d2) {
    float hv0 = hcs[wid][0][d2], hv1 = hcs[wid][1][d2];
    float hv2 = hcs[wid][2][d2], hv3 = hcs[wid][3][d2];
    #pragma unroll
    for (int j = 0; j < 4; ++j) {
      int h = lane + 64 * j;
      float wq = WqT[d2 * 256 + h], wk = WkT[d2 * 256 + h], wc = Wc1T[d2 * 256 + h];
      qv[0][j] = fmaf(wq, hv0, qv[0][j]); qv[1][j] = fmaf(wq, hv1, qv[1][j]);
      qv[2][j] = fmaf(wq, hv2, qv[2][j]); qv[3][j] = fmaf(wq, hv3, qv[3][j]);
      kv[0][j] = fmaf(wk, hv0, kv[0][j]); kv[1][j] = fmaf(wk, hv1, kv[1][j]);
      kv[2][j] = fmaf(wk, hv2, kv[2][j]); kv[3][j] = fmaf(wk, hv3, kv[3][j]);
      cv[0][j] = fmaf(wc, hv0, cv[0][j]); cv[1][j] = fmaf(wc, hv1, cv[1][j]);
      cv[2][j] = fmaf(wc, hv2, cv[2][j]); cv[3][j] = fmaf(wc, hv3, cv[3][j]);
    }
  }
  #pragma unroll
  for (int r = 0; r < 4; ++r)
    #pragma unroll
    for (int j = 0; j < 4; ++j)
      ts[wid][r][lane + 64 * j] = tanhf(qv[r][j] * kv[r][j]);
  __syncthreads();

  float sc[4];
  { float b = bs[lane]; sc[0] = b; sc[1] = b; sc[2] = b; sc[3] = b; }
  for (int h2 = 0; h2 < 256; ++h2) {
    float w = WsT[h2 * 64 + lane];
    sc[0] = fmaf(w, ts[wid][0][h2], sc[0]);
    sc[1] = fmaf(w, ts[wid][1][h2], sc[1]);
    sc[2] = fmaf(w, ts[wid][2][h2], sc[2]);
    sc[3] = fmaf(w, ts[wid][3][h2], sc[3]);
  }

  float hcr[4] = {hc4.x, hc4.y, hc4.z, hc4.w};
  float res[4];
  #pragma unroll
  for (int r = 0; r < 4; ++r) {
    float s = sc[r];
    float mx = s;
    #pragma unroll
    for (int off = 1; off < 64; off <<= 1) mx = fmaxf(mx, __shfl_xor(mx, off));
    float e = __expf(s - mx);
    float se = e;
    #pragma unroll
    for (int off = 1; off < 64; off <<= 1) se += __shfl_xor(se, off);
    float wgt = hcr[r] * (e / se);
    #pragma unroll
    for (int off = 1; off < 64; off <<= 1) wgt += __shfl_xor(wgt, off);
    float cp = 0.f;
    #pragma unroll
    for (int j = 0; j < 4; ++j) cp = fmaf(fmaxf(cv[r][j], 0.f), Wc2[lane + 64 * j], cp);
    #pragma unroll
    for (int off = 1; off < 64; off <<= 1) cp += __shfl_xor(cp, off);
    float comb = wgt + cp + bc2[0];
    float fp = 0.f;
    #pragma unroll
    for (int j = 0; j < 4; ++j) {
      int h = lane + 64 * j;
      fp = fmaf(fmaxf(fmaf(comb, Wg1[h], bg1[h]), 0.f), Wg2[h], fp);
    }
    #pragma unroll
    for (int off = 1; off < 64; off <<= 1) fp += __shfl_xor(fp, off);
    res[r] = fp + bg2[0];
  }
  if (lane == 0) {
    float4 o = make_float4(res[0], res[1], res[2], res[3]);
    *(float4*)(out + r0) = o;
  }
}

extern "C" void kernel_launch(void* const* d_in, const int* in_sizes, int n_in,
                              void* d_out, int out_size, void* d_ws, size_t ws_size,
                              hipStream_t stream) {
  const float* x   = (const float*)d_in[0];
  const float* W1  = (const float*)d_in[1];
  const float* b1  = (const float*)d_in[2];
  const float* W2  = (const float*)d_in[3];
  const float* b2  = (const float*)d_in[4];
  const float* W3  = (const float*)d_in[5];
  const float* b3  = (const float*)d_in[6];
  const float* Wq  = (const float*)d_in[7];
  const float* bq  = (const float*)d_in[8];
  const float* Wk  = (const float*)d_in[9];
  const float* bk  = (const float*)d_in[10];
  const float* Ws  = (const float*)d_in[11];
  const float* bs  = (const float*)d_in[12];
  const float* Wc1 = (const float*)d_in[13];
  const float* bc1 = (const float*)d_in[14];
  const float* Wc2 = (const float*)d_in[15];
  const float* bc2 = (const float*)d_in[16];
  const float* Wg1 = (const float*)d_in[17];
  const float* bg1 = (const float*)d_in[18];
  const float* Wg2 = (const float*)d_in[19];
  const float* bg2 = (const float*)d_in[20];

  unsigned short* Bp = (unsigned short*)d_ws;               // 8,388,608 B
  float* hcT  = (float*)((char*)d_ws + 8388608);            // 4,194,304 B
  float* WqT  = (float*)((char*)d_ws + 12582912);
  float* WkT  = WqT + 16384;
  float* Wc1T = WkT + 16384;
  float* WsT  = Wc1T + 16384;

  pack_w2<<<2048, 256, 0, stream>>>(W2, Bp);
  prep_t<<<64, 256, 0, stream>>>(Wq, Wk, Wc1, Ws, WqT, WkT, Wc1T, WsT);
  gemm_hcat<<<1024, 256, 0, stream>>>(x, W1, b1, b2, W3, b3, Bp, hcT);
  fused_tail<<<1024, 256, 0, stream>>>(hcT, WqT, bq, WkT, bk, WsT, bs, Wc1T, bc1,
                                       Wc2, bc2, Wg1, bg1, Wg2, bg2, (float*)d_out);
}